// Round 1
// baseline (450.312 us; speedup 1.0000x reference)
//
#include <hip/hip_runtime.h>
#include <hip/hip_bf16.h>
#include <stdint.h>

// Problem constants (fixed by reference)
#define TOKENS_C 8192
#define NIN_C    4096
#define NOUT_C   4096
#define GROUP_C  128
#define QZERO_C  8

typedef __bf16 bf16_t;
typedef __bf16  bf16x8 __attribute__((ext_vector_type(8)));
typedef float   f32x4  __attribute__((ext_vector_type(4)));
typedef int     i32x4  __attribute__((ext_vector_type(4)));

#define GAS __attribute__((address_space(1)))
#define LAS __attribute__((address_space(3)))

__device__ __forceinline__ void gload16(const void* g, void* l) {
  __builtin_amdgcn_global_load_lds((const GAS void*)g, (LAS void*)l, 16, 0, 0);
}

// ---------------- pass 1a: dequantize W (int32 codes 0..15) -> bf16 ----------
// W[o,i] = (q[o,i] - 8) * scales[o, i/128].  8 elements / thread.
__global__ __launch_bounds__(256) void dequant_w_kernel(
    const int* __restrict__ qw, const float* __restrict__ sc,
    bf16_t* __restrict__ wb)
{
  const int t = blockIdx.x * 256 + threadIdx.x;
  const int64_t base = (int64_t)t * 8;
  const int o = (int)(base >> 12);          // /4096
  const int i = (int)(base & 4095);
  const float s = sc[(o << 5) | (i >> 7)];  // 32 groups per row; 8 elems stay in one group
  i32x4 q0 = *(const i32x4*)(qw + base);
  i32x4 q1 = *(const i32x4*)(qw + base + 4);
  bf16x8 r;
  r[0] = (bf16_t)((float)(q0[0] - QZERO_C) * s);
  r[1] = (bf16_t)((float)(q0[1] - QZERO_C) * s);
  r[2] = (bf16_t)((float)(q0[2] - QZERO_C) * s);
  r[3] = (bf16_t)((float)(q0[3] - QZERO_C) * s);
  r[4] = (bf16_t)((float)(q1[0] - QZERO_C) * s);
  r[5] = (bf16_t)((float)(q1[1] - QZERO_C) * s);
  r[6] = (bf16_t)((float)(q1[2] - QZERO_C) * s);
  r[7] = (bf16_t)((float)(q1[3] - QZERO_C) * s);
  *(bf16x8*)(wb + base) = r;
}

// ---------------- pass 1b: convert x fp32 -> bf16 ----------------------------
__global__ __launch_bounds__(256) void cvt_x_kernel(
    const float* __restrict__ x, bf16_t* __restrict__ xb)
{
  const int t = blockIdx.x * 256 + threadIdx.x;
  const int64_t base = (int64_t)t * 8;
  f32x4 a = *(const f32x4*)(x + base);
  f32x4 b = *(const f32x4*)(x + base + 4);
  bf16x8 r;
  r[0] = (bf16_t)a[0]; r[1] = (bf16_t)a[1]; r[2] = (bf16_t)a[2]; r[3] = (bf16_t)a[3];
  r[4] = (bf16_t)b[0]; r[5] = (bf16_t)b[1]; r[6] = (bf16_t)b[2]; r[7] = (bf16_t)b[3];
  *(bf16x8*)(xb + base) = r;
}

// ---------------- pass 2: bf16 GEMM, C[M,N] = A[M,K] * B[N,K]^T --------------
// m97 structure: 128x128 tile, BK=32, 256 threads (4 waves, 2x2), 16x16x32 MFMA,
// global_load_lds width 16, linear LDS, 2 barriers per K-step.
#define BM 128
#define BN 128
#define BK 32

__global__ __launch_bounds__(256) void gemm_bt_kernel(
    const bf16_t* __restrict__ A,   // [M][K] bf16 (x)
    const bf16_t* __restrict__ B,   // [N][K] bf16 (W)
    float* __restrict__ C)          // [M][N] f32
{
  constexpr int M = TOKENS_C, N = NOUT_C, K = NIN_C;
  __shared__ alignas(16) bf16_t As[BM][BK];
  __shared__ alignas(16) bf16_t Bs[BN][BK];

  const int t    = threadIdx.x;
  const int lane = t & 63;
  const int wid  = t >> 6;
  const int wm   = wid >> 1;        // wave row (0..1) -> 64 rows of C
  const int wn   = wid & 1;         // wave col (0..1) -> 64 cols of C
  const int bm   = blockIdx.x;      // M/128
  const int bn   = blockIdx.y;      // N/128

  // staging decomposition: thread t copies 8 contiguous bf16 (16 B);
  // LDS dest offset = t*16 B = wave_base + lane*16 (linear, gload_lds-legal)
  const int srow = t >> 2;          // 0..63
  const int scol = (t & 3) << 3;    // 0,8,16,24
  const bf16_t* Ag = A + (int64_t)(bm * BM + srow) * K + scol;
  const bf16_t* Bg = B + (int64_t)(bn * BN + srow) * K + scol;

  // fragment read coords (16x16x32: lane holds 8 contiguous k at k0=(lane>>4)*8)
  const int frow = lane & 15;
  const int fk   = (lane >> 4) << 3;

  f32x4 acc[4][4] = {};

  for (int kt = 0; kt < K; kt += BK) {
    __syncthreads();   // previous tile fully consumed
    gload16(Ag + kt,            &As[srow     ][scol]);
    gload16(Ag + kt + 64 * K,   &As[srow + 64][scol]);
    gload16(Bg + kt,            &Bs[srow     ][scol]);
    gload16(Bg + kt + 64 * K,   &Bs[srow + 64][scol]);
    __syncthreads();   // vmcnt(0) drain emitted by compiler before barrier

    bf16x8 af[4], bfr[4];
#pragma unroll
    for (int i = 0; i < 4; ++i)
      af[i] = *(const bf16x8*)&As[wm * 64 + i * 16 + frow][fk];
#pragma unroll
    for (int j = 0; j < 4; ++j)
      bfr[j] = *(const bf16x8*)&Bs[wn * 64 + j * 16 + frow][fk];

#pragma unroll
    for (int i = 0; i < 4; ++i)
#pragma unroll
      for (int j = 0; j < 4; ++j)
        acc[i][j] = __builtin_amdgcn_mfma_f32_16x16x32_bf16(af[i], bfr[j], acc[i][j], 0, 0, 0);
  }

  // epilogue: C/D layout col=lane&15, row=(lane>>4)*4+r  [m89-verified]
  const int crow0 = bm * BM + wm * 64;
  const int ccol0 = bn * BN + wn * 64;
  const int r0 = (lane >> 4) << 2;
  const int cc = lane & 15;
#pragma unroll
  for (int i = 0; i < 4; ++i)
#pragma unroll
    for (int j = 0; j < 4; ++j) {
      f32x4 v = acc[i][j];
#pragma unroll
      for (int r = 0; r < 4; ++r)
        C[(int64_t)(crow0 + i * 16 + r0 + r) * N + (ccol0 + j * 16 + cc)] = v[r];
    }
}

// ---------------- fallback (only if ws too small): naive fp32 ---------------
__global__ __launch_bounds__(256) void naive_kernel(
    const float* __restrict__ x, const int* __restrict__ qw,
    const float* __restrict__ sc, float* __restrict__ out)
{
  const int64_t idx = (int64_t)blockIdx.x * 256 + threadIdx.x; // TOKENS*NOUT
  const int tok = (int)(idx >> 12);
  const int o   = (int)(idx & 4095);
  const float* xr = x + (int64_t)tok * NIN_C;
  const int* qr = qw + (int64_t)o * NIN_C;
  float acc = 0.f;
  for (int g = 0; g < NIN_C / GROUP_C; ++g) {
    float s = sc[(o << 5) | g];
    float ga = 0.f;
#pragma unroll 4
    for (int i = g * GROUP_C; i < (g + 1) * GROUP_C; ++i)
      ga += xr[i] * (float)(qr[i] - QZERO_C);
    acc += s * ga;
  }
  out[idx] = acc;
}

extern "C" void kernel_launch(void* const* d_in, const int* in_sizes, int n_in,
                              void* d_out, int out_size, void* d_ws, size_t ws_size,
                              hipStream_t stream) {
  const float* x  = (const float*)d_in[0];
  const int*   qw = (const int*)d_in[1];
  const float* sc = (const float*)d_in[2];
  float* out = (float*)d_out;

  const size_t xb_bytes = (size_t)TOKENS_C * NIN_C * sizeof(bf16_t);   // 64 MiB
  const size_t wb_bytes = (size_t)NOUT_C * NIN_C * sizeof(bf16_t);     // 32 MiB

  if (ws_size < xb_bytes + wb_bytes) {
    // correctness fallback (slow): one thread per output element
    const int64_t total = (int64_t)TOKENS_C * NOUT_C;
    naive_kernel<<<(int)(total / 256), 256, 0, stream>>>(x, qw, sc, out);
    return;
  }

  bf16_t* xb = (bf16_t*)d_ws;
  bf16_t* wb = (bf16_t*)((char*)d_ws + xb_bytes);

  {
    const int64_t elems = (int64_t)TOKENS_C * NIN_C;     // 33.5M
    cvt_x_kernel<<<(int)(elems / 8 / 256), 256, 0, stream>>>(x, xb);
  }
  {
    const int64_t elems = (int64_t)NOUT_C * NIN_C;       // 16.8M
    dequant_w_kernel<<<(int)(elems / 8 / 256), 256, 0, stream>>>(qw, sc, wb);
  }
  {
    dim3 grid(TOKENS_C / BM, NOUT_C / BN);               // 64 x 32 = 2048 wg
    gemm_bt_kernel<<<grid, 256, 0, stream>>>(xb, wb, out);
  }
}

// Round 2
// 276.793 us; speedup vs baseline: 1.6269x; 1.6269x over previous
//
#include <hip/hip_runtime.h>
#include <hip/hip_bf16.h>
#include <stdint.h>

// Problem constants (fixed by reference)
#define TOKENS_C 8192
#define NIN_C    4096
#define NOUT_C   4096
#define GROUP_C  128
#define QZERO_C  8

typedef __bf16 bf16_t;
typedef __bf16  bf16x8 __attribute__((ext_vector_type(8)));
typedef float   f32x4  __attribute__((ext_vector_type(4)));
typedef int     i32x4  __attribute__((ext_vector_type(4)));

#define GAS __attribute__((address_space(1)))
#define LAS __attribute__((address_space(3)))

__device__ __forceinline__ void gload16(const void* g, void* l) {
  __builtin_amdgcn_global_load_lds((const GAS void*)g, (LAS void*)l, 16, 0, 0);
}

// ---------------- pass 1a: dequantize W (int32 codes 0..15) -> bf16 ----------
__global__ __launch_bounds__(256) void dequant_w_kernel(
    const int* __restrict__ qw, const float* __restrict__ sc,
    bf16_t* __restrict__ wb)
{
  const int t = blockIdx.x * 256 + threadIdx.x;
  const int64_t base = (int64_t)t * 8;
  const int o = (int)(base >> 12);
  const int i = (int)(base & 4095);
  const float s = sc[(o << 5) | (i >> 7)];
  i32x4 q0 = *(const i32x4*)(qw + base);
  i32x4 q1 = *(const i32x4*)(qw + base + 4);
  bf16x8 r;
  r[0] = (bf16_t)((float)(q0[0] - QZERO_C) * s);
  r[1] = (bf16_t)((float)(q0[1] - QZERO_C) * s);
  r[2] = (bf16_t)((float)(q0[2] - QZERO_C) * s);
  r[3] = (bf16_t)((float)(q0[3] - QZERO_C) * s);
  r[4] = (bf16_t)((float)(q1[0] - QZERO_C) * s);
  r[5] = (bf16_t)((float)(q1[1] - QZERO_C) * s);
  r[6] = (bf16_t)((float)(q1[2] - QZERO_C) * s);
  r[7] = (bf16_t)((float)(q1[3] - QZERO_C) * s);
  *(bf16x8*)(wb + base) = r;
}

// ---------------- pass 1b: convert x fp32 -> bf16 ----------------------------
__global__ __launch_bounds__(256) void cvt_x_kernel(
    const float* __restrict__ x, bf16_t* __restrict__ xb)
{
  const int t = blockIdx.x * 256 + threadIdx.x;
  const int64_t base = (int64_t)t * 8;
  f32x4 a = *(const f32x4*)(x + base);
  f32x4 b = *(const f32x4*)(x + base + 4);
  bf16x8 r;
  r[0] = (bf16_t)a[0]; r[1] = (bf16_t)a[1]; r[2] = (bf16_t)a[2]; r[3] = (bf16_t)a[3];
  r[4] = (bf16_t)b[0]; r[5] = (bf16_t)b[1]; r[6] = (bf16_t)b[2]; r[7] = (bf16_t)b[3];
  *(bf16x8*)(xb + base) = r;
}

// ---------------- pass 2: bf16 GEMM, C[M,N] = A[M,K] * B[N,K]^T --------------
// 256x256 tile, BK=64, 512 threads (8 waves, 2Mx4N), 4 phases per K-tile,
// double-buffered 128KiB LDS, XOR-swizzled (T2), stage-early/drain-late (T3/T4),
// setprio around MFMA clusters (T5).
#define BM 256
#define BN 256
#define BK 64
#define NT (NIN_C / BK)   // 64 K-tiles

__global__ __launch_bounds__(512, 2) void gemm_bt_kernel(
    const bf16_t* __restrict__ A,   // [M][K] bf16 (x)
    const bf16_t* __restrict__ B,   // [N][K] bf16 (W)
    float* __restrict__ C)          // [M][N] f32
{
  constexpr int K = NIN_C, N = NOUT_C;
  // As buf b: smem + b*32768 ; Bs buf b: smem + 65536 + b*32768
  __shared__ char smem[131072];

  const int tid  = threadIdx.x;
  const int lane = tid & 63;
  const int wid  = tid >> 6;       // 0..7
  const int wm   = wid >> 2;       // 0..1  -> 128 rows of C
  const int wn   = wid & 3;        // 0..3  -> 64 cols of C
  const int bm   = blockIdx.x;     // M/256
  const int bn   = blockIdx.y;     // N/256

  // ---- staging geometry ----
  // Each K-tile operand = 256 rows x 64 cols x 2B = 32KB = 32 slots of 1KB.
  // Wave w covers slots w*4..w*4+3; within a slot, lane -> row slot*8+(lane>>3),
  // 16B granule (lane&7). LDS dest is LINEAR (slot*1024 + lane*16); the
  // global SOURCE col-byte is pre-swizzled with the same XOR the reader uses:
  //   LDS(row, g) holds global colbyte (g ^ (row&7))<<4   [involution]
  const int l8   = lane >> 3;                 // row-within-slot 0..7 == row&7
  const int c8   = lane & 7;                  // granule
  const int cswz = ((c8 ^ l8) << 4);          // pre-swizzled source col-byte
  const char* Ab = (const char*)A;
  const char* Bb = (const char*)B;
  int64_t aBase[4], bBase[4];
#pragma unroll
  for (int l = 0; l < 4; ++l) {
    const int slot = (wid << 2) + l;
    aBase[l] = ((int64_t)(bm * BM + slot * 8 + l8) * K) * 2 + cswz;
    bBase[l] = ((int64_t)(bn * BN + slot * 8 + l8) * K) * 2 + cswz;
  }
  const int ldst = ((wid << 2) << 10) + (lane << 4);   // + (l<<10) per load

  // ---- fragment read geometry (16x16x32) ----
  const int frow  = lane & 15;                // row within 16
  const int fcolb = (lane >> 4) << 4;         // k0*2 bytes: 0,16,32,48
  const int rsw   = (lane & 7) << 4;          // (row&7)<<4 (row%8 == lane%8)

  f32x4 acc[8][4] = {};

  // ---- prologue: stage tile 0 into buf 0, full drain ----
  {
    char* Ad = smem;
    char* Bd = smem + 65536;
#pragma unroll
    for (int l = 0; l < 4; ++l) gload16(Ab + aBase[l], Ad + ldst + (l << 10));
#pragma unroll
    for (int l = 0; l < 4; ++l) gload16(Bb + bBase[l], Bd + ldst + (l << 10));
  }
  asm volatile("s_waitcnt vmcnt(0)" ::: "memory");
  __builtin_amdgcn_s_barrier();
  __builtin_amdgcn_sched_barrier(0);

  int cur = 0;
  for (int t = 0; t < NT; ++t) {
    const char* Ar = smem + cur * 32768;
    const char* Br = smem + 65536 + cur * 32768;
    char* Aw = smem + (cur ^ 1) * 32768;
    char* Bw = smem + 65536 + (cur ^ 1) * 32768;
    const int64_t koff = (int64_t)(t + 1) * (BK * 2);  // byte offset of next tile
    const bool pf = (t + 1 < NT);

    bf16x8 a[4], b[4];
#pragma unroll
    for (int p = 0; p < 4; ++p) {
      const int mh = p & 1;       // M-half of wave's 128 rows
      const int kk = p >> 1;      // 32-wide k-step within BK=64

      // prefetch next tile: A-loads in phase 0, B-loads in phase 1 -> loads
      // stay in flight across the remaining phases; drained after phase 3.
      if (p == 0 && pf) {
#pragma unroll
        for (int l = 0; l < 4; ++l) gload16(Ab + aBase[l] + koff, Aw + ldst + (l << 10));
      }
      if (p == 1 && pf) {
#pragma unroll
        for (int l = 0; l < 4; ++l) gload16(Bb + bBase[l] + koff, Bw + ldst + (l << 10));
      }

      const int cb = (kk << 6) + fcolb;       // logical col-byte of fragment
      if (mh == 0) {                          // b-frags reused by both M-halves
#pragma unroll
        for (int j = 0; j < 4; ++j) {
          const int row = wn * 64 + j * 16 + frow;
          b[j] = *(const bf16x8*)(Br + row * 128 + (cb ^ rsw));
        }
      }
#pragma unroll
      for (int i = 0; i < 4; ++i) {
        const int row = wm * 128 + (mh * 4 + i) * 16 + frow;
        a[i] = *(const bf16x8*)(Ar + row * 128 + (cb ^ rsw));
      }

      __builtin_amdgcn_s_setprio(1);
#pragma unroll
      for (int i = 0; i < 4; ++i)
#pragma unroll
        for (int j = 0; j < 4; ++j)
          acc[mh * 4 + i][j] =
              __builtin_amdgcn_mfma_f32_16x16x32_bf16(a[i], b[j], acc[mh * 4 + i][j], 0, 0, 0);
      __builtin_amdgcn_s_setprio(0);
      if (p < 3) __builtin_amdgcn_s_barrier();
    }

    // tile boundary: each wave drains ITS staging loads, then publish buffer
    asm volatile("s_waitcnt vmcnt(0)" ::: "memory");
    __builtin_amdgcn_s_barrier();
    __builtin_amdgcn_sched_barrier(0);
    cur ^= 1;
  }

  // ---- epilogue: C/D layout col=lane&15, row=(lane>>4)*4+r [m89-verified] ----
  const int crow0 = bm * BM + wm * 128;
  const int ccol0 = bn * BN + wn * 64;
  const int r0 = (lane >> 4) << 2;
  const int cc = lane & 15;
#pragma unroll
  for (int fi = 0; fi < 8; ++fi)
#pragma unroll
    for (int j = 0; j < 4; ++j) {
      f32x4 v = acc[fi][j];
#pragma unroll
      for (int r = 0; r < 4; ++r)
        C[(int64_t)(crow0 + fi * 16 + r0 + r) * N + (ccol0 + j * 16 + cc)] = v[r];
    }
}

// ---------------- fallback (only if ws too small): naive fp32 ---------------
__global__ __launch_bounds__(256) void naive_kernel(
    const float* __restrict__ x, const int* __restrict__ qw,
    const float* __restrict__ sc, float* __restrict__ out)
{
  const int64_t idx = (int64_t)blockIdx.x * 256 + threadIdx.x;
  const int tok = (int)(idx >> 12);
  const int o   = (int)(idx & 4095);
  const float* xr = x + (int64_t)tok * NIN_C;
  const int* qr = qw + (int64_t)o * NIN_C;
  float acc = 0.f;
  for (int g = 0; g < NIN_C / GROUP_C; ++g) {
    float s = sc[(o << 5) | g];
    float ga = 0.f;
#pragma unroll 4
    for (int i = g * GROUP_C; i < (g + 1) * GROUP_C; ++i)
      ga += xr[i] * (float)(qr[i] - QZERO_C);
    acc += s * ga;
  }
  out[idx] = acc;
}

extern "C" void kernel_launch(void* const* d_in, const int* in_sizes, int n_in,
                              void* d_out, int out_size, void* d_ws, size_t ws_size,
                              hipStream_t stream) {
  const float* x  = (const float*)d_in[0];
  const int*   qw = (const int*)d_in[1];
  const float* sc = (const float*)d_in[2];
  float* out = (float*)d_out;

  const size_t xb_bytes = (size_t)TOKENS_C * NIN_C * sizeof(bf16_t);   // 64 MiB
  const size_t wb_bytes = (size_t)NOUT_C * NIN_C * sizeof(bf16_t);     // 32 MiB

  if (ws_size < xb_bytes + wb_bytes) {
    const int64_t total = (int64_t)TOKENS_C * NOUT_C;
    naive_kernel<<<(int)(total / 256), 256, 0, stream>>>(x, qw, sc, out);
    return;
  }

  bf16_t* xb = (bf16_t*)d_ws;
  bf16_t* wb = (bf16_t*)((char*)d_ws + xb_bytes);

  {
    const int64_t elems = (int64_t)TOKENS_C * NIN_C;
    cvt_x_kernel<<<(int)(elems / 8 / 256), 256, 0, stream>>>(x, xb);
  }
  {
    const int64_t elems = (int64_t)NOUT_C * NIN_C;
    dequant_w_kernel<<<(int)(elems / 8 / 256), 256, 0, stream>>>(qw, sc, wb);
  }
  {
    dim3 grid(TOKENS_C / BM, NOUT_C / BN);   // 32 x 16 = 512 wg
    gemm_bt_kernel<<<grid, 512, 0, stream>>>(xb, wb, out);
  }
}